// Round 1
// baseline (216.131 us; speedup 1.0000x reference)
//
#include <hip/hip_runtime.h>
#include <hip/hip_bf16.h>

// B=4, N=256, D=256, DL=64
typedef float4 f4;

// ---- workspace layout (float offsets) ----
#define OFF_K     0          // k = x_key@Wk.T + bk       [4*256, 256]
#define OFF_V     262144     // v = x_value@Wvl.T + bvl   [4*256, 256]
#define OFF_Q     524288     // q                          [4, 256]
#define OFF_T2    525312     // T2[b][j][d]                [4, 16384]
#define OFF_T2P   590848     // T2 partials [32 chunks][4][16384]
#define OFF_SNUM  2688000    // raw score numerators       [4, 256]
#define OFF_SD2   2689024    // sum(delta^2)               [4, 256]
#define OFF_ATTN  2690048    // final attention            [4, 256]
#define OFF_BASEP 2691072    // base partials [8][4][256]
#define OFF_S     2699264    // S[b][jd]                   [4, 16384]
// total 2764800 floats = 11.06 MB

// ---------------- q = linear terms + bilinear einsums ----------------
__global__ __launch_bounds__(256) void kq_kernel(
    const float* __restrict__ zq, const float* __restrict__ xq,
    const float* __restrict__ vq, const float* __restrict__ vg,
    const float* __restrict__ Wx, const float* __restrict__ bx,
    const float* __restrict__ Wz, const float* __restrict__ bz,
    const float* __restrict__ Wv, const float* __restrict__ bv,
    const float* __restrict__ wg, const float* __restrict__ wzv,
    float* __restrict__ qout)
{
    __shared__ float zql[4][64], vgl[4][64];
    __shared__ float red[4][256];
    int t = threadIdx.x, o = blockIdx.x;
    zql[t >> 6][t & 63] = zq[t];
    vgl[t >> 6][t & 63] = vg[t];
    __syncthreads();
    float acc[4] = {0.f, 0.f, 0.f, 0.f};
    const float* wgo = wg + o * 4096;
    const float* wzo = wzv + o * 4096;
    for (int f = t; f < 4096; f += 256) {
        float a = wgo[f], c = wzo[f];
        int i = f >> 6, j = f & 63;
        #pragma unroll
        for (int b = 0; b < 4; b++) {
            float h = a * zql[b][j] + c * vgl[b][j];
            acc[b] += zql[b][i] * h;
        }
    }
    float wxv = Wx[o * 256 + t], wvv = Wv[o * 256 + t];
    #pragma unroll
    for (int b = 0; b < 4; b++)
        acc[b] += xq[b * 256 + t] * wxv + vq[b * 256 + t] * wvv;
    if (t < 64) {
        float wzz = Wz[o * 64 + t];
        #pragma unroll
        for (int b = 0; b < 4; b++) acc[b] += zql[b][t] * wzz;
    }
    #pragma unroll
    for (int b = 0; b < 4; b++) red[b][t] = acc[b];
    __syncthreads();
    for (int s = 128; s > 0; s >>= 1) {
        if (t < s) {
            #pragma unroll
            for (int b = 0; b < 4; b++) red[b][t] += red[b][t + s];
        }
        __syncthreads();
    }
    if (t < 4) qout[t * 256 + o] = red[t][0] + bx[o] + bz[o] + bv[o];
}

// ---------------- k/v GEMM: C[r,j] = sum_i A[r,i]*W[j,i] + bias[j] ----------------
// 64x64 tile, 4x4 per thread, K-chunk 32.  grid (16,4,2)
__global__ __launch_bounds__(256) void kkv_kernel(
    const float* __restrict__ xk, const float* __restrict__ xv,
    const float* __restrict__ Wk, const float* __restrict__ bk,
    const float* __restrict__ Wvl, const float* __restrict__ bvl,
    float* __restrict__ ws)
{
    __shared__ float At[32][68];
    __shared__ float Bt[32][68];
    int t = threadIdx.x;
    const float *A, *Wm, *bias;
    float* C;
    if (blockIdx.z == 0) { A = xk; Wm = Wk;  bias = bk;  C = ws + OFF_K; }
    else                 { A = xv; Wm = Wvl; bias = bvl; C = ws + OFF_V; }
    int r0 = blockIdx.x * 64, j0 = blockIdx.y * 64;
    int lr = t >> 2, lk = (t & 3) * 8;
    int tr = t >> 4, tc = t & 15;
    float acc[4][4];
    #pragma unroll
    for (int p = 0; p < 4; p++)
        #pragma unroll
        for (int q = 0; q < 4; q++) acc[p][q] = 0.f;
    for (int kc = 0; kc < 256; kc += 32) {
        f4 a0 = *(const f4*)(A  + (r0 + lr) * 256 + kc + lk);
        f4 a1 = *(const f4*)(A  + (r0 + lr) * 256 + kc + lk + 4);
        f4 b0 = *(const f4*)(Wm + (j0 + lr) * 256 + kc + lk);
        f4 b1 = *(const f4*)(Wm + (j0 + lr) * 256 + kc + lk + 4);
        __syncthreads();
        At[lk + 0][lr] = a0.x; At[lk + 1][lr] = a0.y; At[lk + 2][lr] = a0.z; At[lk + 3][lr] = a0.w;
        At[lk + 4][lr] = a1.x; At[lk + 5][lr] = a1.y; At[lk + 6][lr] = a1.z; At[lk + 7][lr] = a1.w;
        Bt[lk + 0][lr] = b0.x; Bt[lk + 1][lr] = b0.y; Bt[lk + 2][lr] = b0.z; Bt[lk + 3][lr] = b0.w;
        Bt[lk + 4][lr] = b1.x; Bt[lk + 5][lr] = b1.y; Bt[lk + 6][lr] = b1.z; Bt[lk + 7][lr] = b1.w;
        __syncthreads();
        #pragma unroll 8
        for (int kk = 0; kk < 32; kk++) {
            f4 av = *(const f4*)&At[kk][tr * 4];
            f4 bv = *(const f4*)&Bt[kk][tc * 4];
            float aa[4] = {av.x, av.y, av.z, av.w};
            float bb[4] = {bv.x, bv.y, bv.z, bv.w};
            #pragma unroll
            for (int p = 0; p < 4; p++)
                #pragma unroll
                for (int q = 0; q < 4; q++) acc[p][q] += aa[p] * bb[q];
        }
    }
    f4 b4 = *(const f4*)(bias + j0 + tc * 4);
    #pragma unroll
    for (int p = 0; p < 4; p++) {
        f4 o;
        o.x = acc[p][0] + b4.x; o.y = acc[p][1] + b4.y;
        o.z = acc[p][2] + b4.z; o.w = acc[p][3] + b4.w;
        *(f4*)(C + (r0 + tr * 4 + p) * 256 + j0 + tc * 4) = o;
    }
}

// ---------------- theta pass 1: T2 partials[c][b][jd] = sum_{i in chunk} q[b,i]*thc[i,jd] ----------------
// grid (16 jd-blocks of 1024, 32 i-chunks of 8)
__global__ __launch_bounds__(256) void ktheta1_kernel(
    const float* __restrict__ tb, const float* __restrict__ te,
    const float* __restrict__ to, float* __restrict__ ws)
{
    const float* q = ws + OFF_Q;
    float* T2P = ws + OFF_T2P;
    int t = threadIdx.x;
    int jd0 = blockIdx.x * 1024 + t * 4;
    int c = blockIdx.y;
    f4 acc[4];
    #pragma unroll
    for (int b = 0; b < 4; b++) { acc[b].x = 0.f; acc[b].y = 0.f; acc[b].z = 0.f; acc[b].w = 0.f; }
    #pragma unroll
    for (int ii = 0; ii < 8; ii++) {
        int i = c * 8 + ii;
        int off = i * 16384 + jd0;
        f4 a = *(const f4*)(tb + off);
        f4 e = *(const f4*)(te + off);
        f4 o = *(const f4*)(to + off);
        f4 th;
        th.x = a.x + 0.5f * e.x + 0.3f * o.x;
        th.y = a.y + 0.5f * e.y + 0.3f * o.y;
        th.z = a.z + 0.5f * e.z + 0.3f * o.z;
        th.w = a.w + 0.5f * e.w + 0.3f * o.w;
        #pragma unroll
        for (int b = 0; b < 4; b++) {
            float qv = q[b * 256 + i];
            acc[b].x += qv * th.x; acc[b].y += qv * th.y;
            acc[b].z += qv * th.z; acc[b].w += qv * th.w;
        }
    }
    #pragma unroll
    for (int b = 0; b < 4; b++)
        *(f4*)(T2P + (c * 4 + b) * 16384 + jd0) = acc[b];
}

__global__ __launch_bounds__(256) void kt2red_kernel(float* __restrict__ ws)
{
    int idx = blockIdx.x * 256 + threadIdx.x;
    const float* P = ws + OFF_T2P;
    float* T2 = ws + OFF_T2;
    #pragma unroll
    for (int b = 0; b < 4; b++) {
        float s = 0.f;
        for (int c = 0; c < 32; c++) s += P[(c * 4 + b) * 16384 + idx];
        T2[b * 16384 + idx] = s;
    }
}

// ---------------- scores: one wave per (b,n) ----------------
__global__ __launch_bounds__(256) void kscore_kernel(
    const float* __restrict__ zq, const float* __restrict__ zk,
    float* __restrict__ ws)
{
    int t = threadIdx.x;
    int lane = t & 63, wave = t >> 6;
    int b = blockIdx.x >> 6;
    int n = (blockIdx.x & 63) * 4 + wave;
    const float* T2b = ws + OFF_T2 + b * 16384;
    const float* krow = ws + OFF_K + (b * 256 + n) * 256;
    const float* qb = ws + OFF_Q + b * 256;
    float u = 0.f;
    #pragma unroll 4
    for (int j = 0; j < 256; j += 4) {
        f4 k4 = *(const f4*)(krow + j);
        u += T2b[(j + 0) * 64 + lane] * k4.x;
        u += T2b[(j + 1) * 64 + lane] * k4.y;
        u += T2b[(j + 2) * 64 + lane] * k4.z;
        u += T2b[(j + 3) * 64 + lane] * k4.w;
    }
    float qk = 0.f;
    #pragma unroll
    for (int jj = 0; jj < 4; jj++) { int j = jj * 64 + lane; qk += qb[j] * krow[j]; }
    float dlt = zq[b * 64 + lane] - zk[(b * 256 + n) * 64 + lane];
    float v1 = u * dlt;
    float v2 = dlt * dlt;
    #pragma unroll
    for (int off = 32; off > 0; off >>= 1) {
        v1 += __shfl_xor(v1, off, 64);
        v2 += __shfl_xor(v2, off, 64);
        qk += __shfl_xor(qk, off, 64);
    }
    if (lane == 0) {
        ws[OFF_SNUM + b * 256 + n] = qk - v1;
        ws[OFF_SD2  + b * 256 + n] = v2;
    }
}

// ---------------- softmax + screening + renorm ----------------
__global__ __launch_bounds__(256) void ksm_kernel(
    const float* __restrict__ zq, const int* __restrict__ level,
    float* __restrict__ ws, float* __restrict__ dout)
{
    __shared__ float sh[256];
    int t = threadIdx.x, b = blockIdx.x;
    float zv = (t < 64) ? zq[b * 64 + t] : 0.f;
    sh[t] = zv * zv;
    __syncthreads();
    for (int s = 128; s > 0; s >>= 1) { if (t < s) sh[t] += sh[t + s]; __syncthreads(); }
    float ns = sh[0];
    __syncthreads();
    float lam = 2.f / (1.f - ns + 1e-6f);
    float tau = 16.f / lam;                 // sqrt(256)/lam
    float sigma = expf(-(float)level[0]);   // G_S=1.0
    float sc = ws[OFF_SNUM + b * 256 + t] / (tau + 1e-6f);
    sh[t] = sc; __syncthreads();
    for (int s = 128; s > 0; s >>= 1) { if (t < s) sh[t] = fmaxf(sh[t], sh[t + s]); __syncthreads(); }
    float m = sh[0]; __syncthreads();
    float e = expf(sc - m);
    sh[t] = e; __syncthreads();
    for (int s = 128; s > 0; s >>= 1) { if (t < s) sh[t] += sh[t + s]; __syncthreads(); }
    float Z = sh[0]; __syncthreads();
    float a = e / Z;
    a *= expf(-sigma * 0.5f * lam * lam * ws[OFF_SD2 + b * 256 + t]);
    sh[t] = a; __syncthreads();
    for (int s = 128; s > 0; s >>= 1) { if (t < s) sh[t] += sh[t + s]; __syncthreads(); }
    float Z2 = sh[0];
    float af = a / (Z2 + 1e-6f);
    dout[1024 + b * 256 + t] = af;     // attention output
    ws[OFF_ATTN + b * 256 + t] = af;
}

// ---------------- base partials: base[b,i] = sum_n a_n * v[b,n,i] ----------------
__global__ __launch_bounds__(256) void kbase_kernel(float* __restrict__ ws)
{
    int t = threadIdx.x;
    int c = blockIdx.x, b = blockIdx.y;
    const float* attn = ws + OFF_ATTN + b * 256;
    const float* v = ws + OFF_V + b * 256 * 256;
    float acc = 0.f;
    #pragma unroll 8
    for (int nn = 0; nn < 32; nn++) {
        int n = c * 32 + nn;
        acc += attn[n] * v[n * 256 + t];
    }
    ws[OFF_BASEP + (c * 4 + b) * 256 + t] = acc;
}

// ---------------- S[b][jd] = sum_n a_n * v[b,n,j] * delta[b,n,d] ----------------
__global__ __launch_bounds__(256) void ks_kernel(
    const float* __restrict__ zq, const float* __restrict__ zk,
    float* __restrict__ ws)
{
    int t = threadIdx.x;
    int b = blockIdx.x >> 6;
    int jd = (blockIdx.x & 63) * 256 + t;
    int j = jd >> 6, dd = jd & 63;
    const float* attn = ws + OFF_ATTN + b * 256;
    const float* v = ws + OFF_V + b * 256 * 256;
    const float* zkb = zk + b * 256 * 64;
    float zqv = zq[b * 64 + dd];
    float acc = 0.f;
    #pragma unroll 4
    for (int n = 0; n < 256; n++) {
        float a = attn[n];
        float vv = v[n * 256 + j];
        float d = zqv - zkb[n * 64 + dd];
        acc += a * vv * d;
    }
    ws[OFF_S + b * 16384 + jd] = acc;
}

// ---------------- theta pass 2: out[b,i] = base - sum_jd thc[i,jd]*S[b,jd] ----------------
__global__ __launch_bounds__(256) void kout_kernel(
    const float* __restrict__ tb, const float* __restrict__ te,
    const float* __restrict__ to, float* __restrict__ ws,
    float* __restrict__ dout)
{
    __shared__ float red[4][256];
    int t = threadIdx.x, i = blockIdx.x;
    const float* S = ws + OFF_S;
    float acc[4] = {0.f, 0.f, 0.f, 0.f};
    #pragma unroll 4
    for (int f = 0; f < 16; f++) {
        int jd = f * 1024 + t * 4;
        int off = i * 16384 + jd;
        f4 a = *(const f4*)(tb + off);
        f4 e = *(const f4*)(te + off);
        f4 o = *(const f4*)(to + off);
        f4 th;
        th.x = a.x + 0.5f * e.x + 0.3f * o.x;
        th.y = a.y + 0.5f * e.y + 0.3f * o.y;
        th.z = a.z + 0.5f * e.z + 0.3f * o.z;
        th.w = a.w + 0.5f * e.w + 0.3f * o.w;
        #pragma unroll
        for (int b = 0; b < 4; b++) {
            f4 s4 = *(const f4*)(S + b * 16384 + jd);
            acc[b] += th.x * s4.x + th.y * s4.y + th.z * s4.z + th.w * s4.w;
        }
    }
    #pragma unroll
    for (int b = 0; b < 4; b++) red[b][t] = acc[b];
    __syncthreads();
    for (int s = 128; s > 0; s >>= 1) {
        if (t < s) {
            #pragma unroll
            for (int b = 0; b < 4; b++) red[b][t] += red[b][t + s];
        }
        __syncthreads();
    }
    if (t < 4) {
        float bs = 0.f;
        #pragma unroll
        for (int c = 0; c < 8; c++) bs += ws[OFF_BASEP + (c * 4 + t) * 256 + i];
        dout[t * 256 + i] = bs - red[t][0];
    }
}

extern "C" void kernel_launch(void* const* d_in, const int* in_sizes, int n_in,
                              void* d_out, int out_size, void* d_ws, size_t ws_size,
                              hipStream_t stream)
{
    (void)in_sizes; (void)n_in; (void)out_size; (void)ws_size;
    const float* zq  = (const float*)d_in[0];
    const float* zk  = (const float*)d_in[1];
    const float* xq  = (const float*)d_in[2];
    const float* xk  = (const float*)d_in[3];
    const float* xv  = (const float*)d_in[4];
    const float* vq  = (const float*)d_in[5];
    const float* vg  = (const float*)d_in[6];
    const float* Wx  = (const float*)d_in[7];
    const float* bx  = (const float*)d_in[8];
    const float* Wz  = (const float*)d_in[9];
    const float* bz  = (const float*)d_in[10];
    const float* Wv  = (const float*)d_in[11];
    const float* bv  = (const float*)d_in[12];
    const float* wg  = (const float*)d_in[13];
    const float* wzv = (const float*)d_in[14];
    const float* Wk  = (const float*)d_in[15];
    const float* bk  = (const float*)d_in[16];
    const float* Wvl = (const float*)d_in[17];
    const float* bvl = (const float*)d_in[18];
    const float* tb  = (const float*)d_in[19];
    const float* te  = (const float*)d_in[20];
    const float* to  = (const float*)d_in[21];
    const int* level = (const int*)d_in[22];
    float* ws = (float*)d_ws;
    float* dout = (float*)d_out;

    kq_kernel<<<dim3(256), dim3(256), 0, stream>>>(zq, xq, vq, vg, Wx, bx, Wz, bz, Wv, bv, wg, wzv, ws + OFF_Q);
    kkv_kernel<<<dim3(16, 4, 2), dim3(256), 0, stream>>>(xk, xv, Wk, bk, Wvl, bvl, ws);
    ktheta1_kernel<<<dim3(16, 32), dim3(256), 0, stream>>>(tb, te, to, ws);
    kt2red_kernel<<<dim3(64), dim3(256), 0, stream>>>(ws);
    kscore_kernel<<<dim3(256), dim3(256), 0, stream>>>(zq, zk, ws);
    ksm_kernel<<<dim3(4), dim3(256), 0, stream>>>(zq, level, ws, dout);
    kbase_kernel<<<dim3(8, 4), dim3(256), 0, stream>>>(ws);
    ks_kernel<<<dim3(256), dim3(256), 0, stream>>>(zq, zk, ws);
    kout_kernel<<<dim3(256), dim3(256), 0, stream>>>(tb, te, to, ws, dout);
}

// Round 2
// 193.584 us; speedup vs baseline: 1.1165x; 1.1165x over previous
//
#include <hip/hip_runtime.h>
#include <hip/hip_bf16.h>

// B=4, N=256, D=256, DL=64
typedef float4 f4;

// ---- workspace layout (float offsets) ----
#define OFF_K     0          // k = x_key@Wk.T + bk       [4*256, 256]
#define OFF_V     262144     // v = x_value@Wvl.T + bvl   [4*256, 256]
#define OFF_Q     524288     // q                          [4, 256]
#define OFF_T2    525312     // T2[b][j][d]                [4, 16384]
#define OFF_T2P   590848     // T2 partials [32][4][16384]
#define OFF_SNUMP 2688000    // score-num partials [4dt][4b][256]
#define OFF_SD2P  2692096    // sum(delta^2) partials [4dt][4b][256]
#define OFF_ATTN  2696192    // final attention            [4, 256]
#define OFF_BASE  2697216    // base[b][i]                 [4, 256]
#define OFF_S     2698240    // S[b][jd]                   [4, 16384]
// total 2763776 floats = 11.06 MB

// =====================================================================
// K1: fused q-projection (blocks 0..255) + k/v GEMM (blocks 256..383)
// =====================================================================
__global__ __launch_bounds__(256) void kprep_kernel(
    const float* __restrict__ zq, const float* __restrict__ xq,
    const float* __restrict__ vq, const float* __restrict__ vg,
    const float* __restrict__ Wx, const float* __restrict__ bx,
    const float* __restrict__ Wz, const float* __restrict__ bz,
    const float* __restrict__ Wv, const float* __restrict__ bv,
    const float* __restrict__ wg, const float* __restrict__ wzv,
    const float* __restrict__ xk, const float* __restrict__ xv,
    const float* __restrict__ Wk, const float* __restrict__ bk,
    const float* __restrict__ Wvl, const float* __restrict__ bvl,
    float* __restrict__ ws)
{
    __shared__ float zql[4][64], vgl[4][64];
    __shared__ float red[4][256];
    __shared__ float At[32][68];
    __shared__ float Bt[32][68];
    int t = threadIdx.x;

    if (blockIdx.x < 256) {
        // ---------------- q path ----------------
        int o = blockIdx.x;
        zql[t >> 6][t & 63] = zq[t];
        vgl[t >> 6][t & 63] = vg[t];
        __syncthreads();
        float acc[4] = {0.f, 0.f, 0.f, 0.f};
        const float* wgo = wg + o * 4096;
        const float* wzo = wzv + o * 4096;
        for (int f = t; f < 4096; f += 256) {
            float a = wgo[f], c = wzo[f];
            int i = f >> 6, j = f & 63;
            #pragma unroll
            for (int b = 0; b < 4; b++) {
                float h = a * zql[b][j] + c * vgl[b][j];
                acc[b] += zql[b][i] * h;
            }
        }
        float wxv = Wx[o * 256 + t], wvv = Wv[o * 256 + t];
        #pragma unroll
        for (int b = 0; b < 4; b++)
            acc[b] += xq[b * 256 + t] * wxv + vq[b * 256 + t] * wvv;
        if (t < 64) {
            float wzz = Wz[o * 64 + t];
            #pragma unroll
            for (int b = 0; b < 4; b++) acc[b] += zql[b][t] * wzz;
        }
        #pragma unroll
        for (int b = 0; b < 4; b++) red[b][t] = acc[b];
        __syncthreads();
        for (int s = 128; s > 0; s >>= 1) {
            if (t < s) {
                #pragma unroll
                for (int b = 0; b < 4; b++) red[b][t] += red[b][t + s];
            }
            __syncthreads();
        }
        if (t < 4) ws[OFF_Q + t * 256 + o] = red[t][0] + bx[o] + bz[o] + bv[o];
        return;
    }

    // ---------------- k/v GEMM path ----------------
    int idx = blockIdx.x - 256;          // 0..127
    int which = idx >> 6;                // 0: k, 1: v
    int rem = idx & 63;
    int rt = rem & 15, jt = rem >> 4;
    const float *A, *Wm, *bias;
    float* C;
    if (which == 0) { A = xk; Wm = Wk;  bias = bk;  C = ws + OFF_K; }
    else            { A = xv; Wm = Wvl; bias = bvl; C = ws + OFF_V; }
    int r0 = rt * 64, j0 = jt * 64;
    int lr = t >> 2, lk = (t & 3) * 8;
    int tr = t >> 4, tc = t & 15;
    float acc[4][4];
    #pragma unroll
    for (int p = 0; p < 4; p++)
        #pragma unroll
        for (int q = 0; q < 4; q++) acc[p][q] = 0.f;
    for (int kc = 0; kc < 256; kc += 32) {
        f4 a0 = *(const f4*)(A  + (r0 + lr) * 256 + kc + lk);
        f4 a1 = *(const f4*)(A  + (r0 + lr) * 256 + kc + lk + 4);
        f4 b0 = *(const f4*)(Wm + (j0 + lr) * 256 + kc + lk);
        f4 b1 = *(const f4*)(Wm + (j0 + lr) * 256 + kc + lk + 4);
        __syncthreads();
        At[lk + 0][lr] = a0.x; At[lk + 1][lr] = a0.y; At[lk + 2][lr] = a0.z; At[lk + 3][lr] = a0.w;
        At[lk + 4][lr] = a1.x; At[lk + 5][lr] = a1.y; At[lk + 6][lr] = a1.z; At[lk + 7][lr] = a1.w;
        Bt[lk + 0][lr] = b0.x; Bt[lk + 1][lr] = b0.y; Bt[lk + 2][lr] = b0.z; Bt[lk + 3][lr] = b0.w;
        Bt[lk + 4][lr] = b1.x; Bt[lk + 5][lr] = b1.y; Bt[lk + 6][lr] = b1.z; Bt[lk + 7][lr] = b1.w;
        __syncthreads();
        #pragma unroll 8
        for (int kk = 0; kk < 32; kk++) {
            f4 av = *(const f4*)&At[kk][tr * 4];
            f4 bv4 = *(const f4*)&Bt[kk][tc * 4];
            float aa[4] = {av.x, av.y, av.z, av.w};
            float bb[4] = {bv4.x, bv4.y, bv4.z, bv4.w};
            #pragma unroll
            for (int p = 0; p < 4; p++)
                #pragma unroll
                for (int q = 0; q < 4; q++) acc[p][q] += aa[p] * bb[q];
        }
    }
    f4 b4 = *(const f4*)(bias + j0 + tc * 4);
    #pragma unroll
    for (int p = 0; p < 4; p++) {
        f4 o;
        o.x = acc[p][0] + b4.x; o.y = acc[p][1] + b4.y;
        o.z = acc[p][2] + b4.z; o.w = acc[p][3] + b4.w;
        *(f4*)(C + (r0 + tr * 4 + p) * 256 + j0 + tc * 4) = o;
    }
}

// =====================================================================
// K2: theta pass 1 partials: T2P[c][b][jd] = sum_{i in chunk} q[b,i]*th[i,jd]
// grid (16 jd-blocks of 1024, 32 i-chunks of 8)
// =====================================================================
__global__ __launch_bounds__(256) void ktheta1_kernel(
    const float* __restrict__ tb, const float* __restrict__ te,
    const float* __restrict__ to, float* __restrict__ ws)
{
    const float* q = ws + OFF_Q;
    float* T2P = ws + OFF_T2P;
    int t = threadIdx.x;
    int jd0 = blockIdx.x * 1024 + t * 4;
    int c = blockIdx.y;
    f4 acc[4];
    #pragma unroll
    for (int b = 0; b < 4; b++) { acc[b].x = 0.f; acc[b].y = 0.f; acc[b].z = 0.f; acc[b].w = 0.f; }
    #pragma unroll
    for (int ii = 0; ii < 8; ii++) {
        int i = c * 8 + ii;
        int off = i * 16384 + jd0;
        f4 a = *(const f4*)(tb + off);
        f4 e = *(const f4*)(te + off);
        f4 o = *(const f4*)(to + off);
        f4 th;
        th.x = a.x + 0.5f * e.x + 0.3f * o.x;
        th.y = a.y + 0.5f * e.y + 0.3f * o.y;
        th.z = a.z + 0.5f * e.z + 0.3f * o.z;
        th.w = a.w + 0.5f * e.w + 0.3f * o.w;
        #pragma unroll
        for (int b = 0; b < 4; b++) {
            float qv = q[b * 256 + i];
            acc[b].x += qv * th.x; acc[b].y += qv * th.y;
            acc[b].z += qv * th.z; acc[b].w += qv * th.w;
        }
    }
    #pragma unroll
    for (int b = 0; b < 4; b++)
        *(f4*)(T2P + (c * 4 + b) * 16384 + jd0) = acc[b];
}

__global__ __launch_bounds__(256) void kt2red_kernel(float* __restrict__ ws)
{
    int idx = blockIdx.x * 256 + threadIdx.x;
    const float* P = ws + OFF_T2P;
    float* T2 = ws + OFF_T2;
    #pragma unroll
    for (int b = 0; b < 4; b++) {
        float s = 0.f;
        for (int c = 0; c < 32; c++) s += P[(c * 4 + b) * 16384 + idx];
        T2[b * 16384 + idx] = s;
    }
}

// =====================================================================
// K3: GEMM-shaped scores.  M[n,d] = sum_j k[b,n,j]*T2[b,j,d]; fold qk.
// grid (16 = 4b x 4ntile, 4 dtile).  Writes SNUMP/SD2P partials.
// =====================================================================
__global__ __launch_bounds__(256) void kscore2_kernel(
    const float* __restrict__ zq, const float* __restrict__ zk,
    float* __restrict__ ws)
{
    __shared__ float kls[64][33];
    __shared__ float t2ls[32][16];
    __shared__ float qls[32];
    int t = threadIdx.x;
    int bx = blockIdx.x;
    int b = bx >> 2, nt = bx & 3;
    int dt = blockIdx.y;
    int nl = t >> 2, dq = t & 3;
    int n = nt * 64 + nl;
    const float* kb = ws + OFF_K + (b * 256 + nt * 64) * 256;
    const float* T2b = ws + OFF_T2 + b * 16384;
    const float* qb = ws + OFF_Q + b * 256;
    float acc[4] = {0.f, 0.f, 0.f, 0.f};
    float qk = 0.f;
    for (int j0 = 0; j0 < 256; j0 += 32) {
        __syncthreads();
        {   // stage k tile [64n x 32j]
            int row = t >> 2, col = (t & 3) * 8;
            f4 a0 = *(const f4*)(kb + row * 256 + j0 + col);
            f4 a1 = *(const f4*)(kb + row * 256 + j0 + col + 4);
            kls[row][col + 0] = a0.x; kls[row][col + 1] = a0.y;
            kls[row][col + 2] = a0.z; kls[row][col + 3] = a0.w;
            kls[row][col + 4] = a1.x; kls[row][col + 5] = a1.y;
            kls[row][col + 6] = a1.z; kls[row][col + 7] = a1.w;
        }
        {   // stage T2 tile [32j x 16d]
            int e = t * 2; int jj = e >> 4; int dd = e & 15;
            const float* p = T2b + (j0 + jj) * 64 + dt * 16 + dd;
            t2ls[jj][dd] = p[0];
            t2ls[jj][dd + 1] = p[1];
        }
        if (t < 32) qls[t] = qb[j0 + t];
        __syncthreads();
        #pragma unroll
        for (int jj = 0; jj < 32; jj++) {
            float kv = kls[nl][jj];
            f4 t4 = *(const f4*)&t2ls[jj][dq * 4];
            acc[0] += kv * t4.x; acc[1] += kv * t4.y;
            acc[2] += kv * t4.z; acc[3] += kv * t4.w;
            qk += kv * qls[jj];
        }
    }
    int d0 = dt * 16 + dq * 4;
    f4 zq4 = *(const f4*)(zq + b * 64 + d0);
    f4 zk4 = *(const f4*)(zk + (b * 256 + n) * 64 + d0);
    float dx = zq4.x - zk4.x, dy = zq4.y - zk4.y;
    float dz = zq4.z - zk4.z, dw = zq4.w - zk4.w;
    float s1 = acc[0] * dx + acc[1] * dy + acc[2] * dz + acc[3] * dw;
    float s2 = dx * dx + dy * dy + dz * dz + dw * dw;
    s1 += __shfl_xor(s1, 1, 64); s1 += __shfl_xor(s1, 2, 64);
    s2 += __shfl_xor(s2, 1, 64); s2 += __shfl_xor(s2, 2, 64);
    if (dq == 0) {
        ws[OFF_SNUMP + (dt * 4 + b) * 256 + n] = (dt == 0 ? qk : 0.f) - s1;
        ws[OFF_SD2P  + (dt * 4 + b) * 256 + n] = s2;
    }
}

// =====================================================================
// K4: softmax + screening + renorm.  grid 4 blocks (one per b).
// =====================================================================
__global__ __launch_bounds__(256) void ksm2_kernel(
    const float* __restrict__ zq, const int* __restrict__ level,
    float* __restrict__ ws, float* __restrict__ dout)
{
    __shared__ float sh[4];
    __shared__ float lamsh;
    int t = threadIdx.x, b = blockIdx.x;
    if (t < 64) {
        float zv = zq[b * 64 + t];
        float v = zv * zv;
        #pragma unroll
        for (int off = 32; off; off >>= 1) v += __shfl_xor(v, off, 64);
        if (t == 0) lamsh = 2.f / (1.f - v + 1e-6f);
    }
    __syncthreads();
    float lam = lamsh;
    float tau = 16.f / lam;
    float sigma = expf(-(float)level[0]);
    float snum = 0.f, sd2 = 0.f;
    #pragma unroll
    for (int dt = 0; dt < 4; dt++) {
        snum += ws[OFF_SNUMP + (dt * 4 + b) * 256 + t];
        sd2  += ws[OFF_SD2P  + (dt * 4 + b) * 256 + t];
    }
    float sc = snum / (tau + 1e-6f);
    int wid = t >> 6;
    float m = sc;
    #pragma unroll
    for (int off = 32; off; off >>= 1) m = fmaxf(m, __shfl_xor(m, off, 64));
    if ((t & 63) == 0) sh[wid] = m;
    __syncthreads();
    m = fmaxf(fmaxf(sh[0], sh[1]), fmaxf(sh[2], sh[3]));
    __syncthreads();
    float e = expf(sc - m);
    float s = e;
    #pragma unroll
    for (int off = 32; off; off >>= 1) s += __shfl_xor(s, off, 64);
    if ((t & 63) == 0) sh[wid] = s;
    __syncthreads();
    float Z = sh[0] + sh[1] + sh[2] + sh[3];
    __syncthreads();
    float a = (e / Z) * expf(-sigma * 0.5f * lam * lam * sd2);
    s = a;
    #pragma unroll
    for (int off = 32; off; off >>= 1) s += __shfl_xor(s, off, 64);
    if ((t & 63) == 0) sh[wid] = s;
    __syncthreads();
    float Z2 = sh[0] + sh[1] + sh[2] + sh[3];
    float af = a / (Z2 + 1e-6f);
    dout[1024 + b * 256 + t] = af;
    ws[OFF_ATTN + b * 256 + t] = af;
}

// =====================================================================
// K5: S[b,j,d] = sum_n a_n v[b,n,j] delta[b,n,d]; base folded in.
// grid 64 = 4b x 16 jtile(16j).  thread: j_local = t>>4, d0 = (t&15)*4.
// =====================================================================
__global__ __launch_bounds__(256) void ks2_kernel(
    const float* __restrict__ zq, const float* __restrict__ zk,
    float* __restrict__ ws)
{
    __shared__ float vls[32][17];
    __shared__ float dls[32][64];
    __shared__ float als[32];
    __shared__ float zqs[64];
    int t = threadIdx.x;
    int b = blockIdx.x >> 4, jt = blockIdx.x & 15;
    int jl = t >> 4, dq = t & 15, d0 = dq * 4;
    const float* vb = ws + OFF_V + b * 65536;
    const float* ab = ws + OFF_ATTN + b * 256;
    const float* zkb = zk + b * 16384;
    if (t < 64) zqs[t] = zq[b * 64 + t];
    float acc[4] = {0.f, 0.f, 0.f, 0.f};
    float bacc = 0.f;
    for (int n0 = 0; n0 < 256; n0 += 32) {
        __syncthreads();
        {   // stage v [32n x 16j]
            int e = t * 2; int nn = e >> 4; int jj = e & 15;
            const float* p = vb + (n0 + nn) * 256 + jt * 16 + jj;
            vls[nn][jj] = p[0];
            vls[nn][jj + 1] = p[1];
        }
        {   // stage delta [32n x 64d]
            int e = t * 8; int nn = e >> 6; int dd = e & 63;
            f4 a = *(const f4*)(zkb + (n0 + nn) * 64 + dd);
            f4 b4 = *(const f4*)(zkb + (n0 + nn) * 64 + dd + 4);
            dls[nn][dd + 0] = zqs[dd + 0] - a.x;
            dls[nn][dd + 1] = zqs[dd + 1] - a.y;
            dls[nn][dd + 2] = zqs[dd + 2] - a.z;
            dls[nn][dd + 3] = zqs[dd + 3] - a.w;
            dls[nn][dd + 4] = zqs[dd + 4] - b4.x;
            dls[nn][dd + 5] = zqs[dd + 5] - b4.y;
            dls[nn][dd + 6] = zqs[dd + 6] - b4.z;
            dls[nn][dd + 7] = zqs[dd + 7] - b4.w;
        }
        if (t < 32) als[t] = ab[n0 + t];
        __syncthreads();
        #pragma unroll
        for (int nn = 0; nn < 32; nn++) {
            float avv = als[nn] * vls[nn][jl];
            f4 d4 = *(const f4*)&dls[nn][d0];
            acc[0] += avv * d4.x; acc[1] += avv * d4.y;
            acc[2] += avv * d4.z; acc[3] += avv * d4.w;
            bacc += avv;
        }
    }
    float* Sb = ws + OFF_S + b * 16384;
    f4 o; o.x = acc[0]; o.y = acc[1]; o.z = acc[2]; o.w = acc[3];
    *(f4*)(Sb + (jt * 16 + jl) * 64 + d0) = o;
    if (dq == 0) ws[OFF_BASE + b * 256 + jt * 16 + jl] = bacc;
}

// =====================================================================
// K6: theta pass 2: out[b,i] = base[b,i] - sum_jd th[i,jd]*S[b,jd]
// =====================================================================
__global__ __launch_bounds__(256) void kout_kernel(
    const float* __restrict__ tb, const float* __restrict__ te,
    const float* __restrict__ to, float* __restrict__ ws,
    float* __restrict__ dout)
{
    __shared__ float red[4][256];
    int t = threadIdx.x, i = blockIdx.x;
    const float* S = ws + OFF_S;
    float acc[4] = {0.f, 0.f, 0.f, 0.f};
    #pragma unroll 4
    for (int f = 0; f < 16; f++) {
        int jd = f * 1024 + t * 4;
        int off = i * 16384 + jd;
        f4 a = *(const f4*)(tb + off);
        f4 e = *(const f4*)(te + off);
        f4 o = *(const f4*)(to + off);
        f4 th;
        th.x = a.x + 0.5f * e.x + 0.3f * o.x;
        th.y = a.y + 0.5f * e.y + 0.3f * o.y;
        th.z = a.z + 0.5f * e.z + 0.3f * o.z;
        th.w = a.w + 0.5f * e.w + 0.3f * o.w;
        #pragma unroll
        for (int b = 0; b < 4; b++) {
            f4 s4 = *(const f4*)(S + b * 16384 + jd);
            acc[b] += th.x * s4.x + th.y * s4.y + th.z * s4.z + th.w * s4.w;
        }
    }
    #pragma unroll
    for (int b = 0; b < 4; b++) red[b][t] = acc[b];
    __syncthreads();
    for (int s = 128; s > 0; s >>= 1) {
        if (t < s) {
            #pragma unroll
            for (int b = 0; b < 4; b++) red[b][t] += red[b][t + s];
        }
        __syncthreads();
    }
    if (t < 4) {
        float bs = ws[OFF_BASE + t * 256 + i];
        dout[t * 256 + i] = bs - red[t][0];
    }
}

extern "C" void kernel_launch(void* const* d_in, const int* in_sizes, int n_in,
                              void* d_out, int out_size, void* d_ws, size_t ws_size,
                              hipStream_t stream)
{
    (void)in_sizes; (void)n_in; (void)out_size; (void)ws_size;
    const float* zq  = (const float*)d_in[0];
    const float* zk  = (const float*)d_in[1];
    const float* xq  = (const float*)d_in[2];
    const float* xk  = (const float*)d_in[3];
    const float* xv  = (const float*)d_in[4];
    const float* vq  = (const float*)d_in[5];
    const float* vg  = (const float*)d_in[6];
    const float* Wx  = (const float*)d_in[7];
    const float* bx  = (const float*)d_in[8];
    const float* Wz  = (const float*)d_in[9];
    const float* bz  = (const float*)d_in[10];
    const float* Wv  = (const float*)d_in[11];
    const float* bv  = (const float*)d_in[12];
    const float* wg  = (const float*)d_in[13];
    const float* wzv = (const float*)d_in[14];
    const float* Wk  = (const float*)d_in[15];
    const float* bk  = (const float*)d_in[16];
    const float* Wvl = (const float*)d_in[17];
    const float* bvl = (const float*)d_in[18];
    const float* tb  = (const float*)d_in[19];
    const float* te  = (const float*)d_in[20];
    const float* to  = (const float*)d_in[21];
    const int* level = (const int*)d_in[22];
    float* ws = (float*)d_ws;
    float* dout = (float*)d_out;

    kprep_kernel<<<dim3(384), dim3(256), 0, stream>>>(
        zq, xq, vq, vg, Wx, bx, Wz, bz, Wv, bv, wg, wzv,
        xk, xv, Wk, bk, Wvl, bvl, ws);
    ktheta1_kernel<<<dim3(16, 32), dim3(256), 0, stream>>>(tb, te, to, ws);
    kt2red_kernel<<<dim3(64), dim3(256), 0, stream>>>(ws);
    kscore2_kernel<<<dim3(16, 4), dim3(256), 0, stream>>>(zq, zk, ws);
    ksm2_kernel<<<dim3(4), dim3(256), 0, stream>>>(zq, level, ws, dout);
    ks2_kernel<<<dim3(64), dim3(256), 0, stream>>>(zq, zk, ws);
    kout_kernel<<<dim3(256), dim3(256), 0, stream>>>(tb, te, to, ws, dout);
}

// Round 3
// 190.181 us; speedup vs baseline: 1.1364x; 1.0179x over previous
//
#include <hip/hip_runtime.h>
#include <hip/hip_bf16.h>

// B=4, N=256, D=256, DL=64
typedef float4 f4;

// ---- workspace layout (float offsets) ----
#define OFF_K     0          // k = x_key@Wk.T + bk       [4*256, 256]
#define OFF_V     262144     // v = x_value@Wvl.T + bvl   [4*256, 256]
#define OFF_Q     524288     // q                          [4, 256]
#define OFF_T2    525312     // T2[b][j][d]                [4, 16384]
#define OFF_SNUMP 590848     // score-num partials [4dt][4b][256]
#define OFF_SD2P  594944     // sum(delta^2) partials [4dt][4b][256]
#define OFF_BASE  599040     // base[b][i]                 [4, 256]
#define OFF_S     600064     // S[b][jd]                   [4, 16384]
#define OFF_TH    665600     // combined theta [256][16384]
// total 4859904 floats = 19.4 MB

// =====================================================================
// K1: fused q-projection (blocks 0..255) + k/v GEMM (blocks 256..383)
// =====================================================================
__global__ __launch_bounds__(256) void kprep_kernel(
    const float* __restrict__ zq, const float* __restrict__ xq,
    const float* __restrict__ vq, const float* __restrict__ vg,
    const float* __restrict__ Wx, const float* __restrict__ bx,
    const float* __restrict__ Wz, const float* __restrict__ bz,
    const float* __restrict__ Wv, const float* __restrict__ bv,
    const float* __restrict__ wg, const float* __restrict__ wzv,
    const float* __restrict__ xk, const float* __restrict__ xv,
    const float* __restrict__ Wk, const float* __restrict__ bk,
    const float* __restrict__ Wvl, const float* __restrict__ bvl,
    float* __restrict__ ws)
{
    __shared__ float zql[4][64], vgl[4][64];
    __shared__ float red[4][256];
    __shared__ float At[32][68];
    __shared__ float Bt[32][68];
    int t = threadIdx.x;

    if (blockIdx.x < 256) {
        // ---------------- q path ----------------
        int o = blockIdx.x;
        zql[t >> 6][t & 63] = zq[t];
        vgl[t >> 6][t & 63] = vg[t];
        __syncthreads();
        float acc[4] = {0.f, 0.f, 0.f, 0.f};
        const float* wgo = wg + o * 4096;
        const float* wzo = wzv + o * 4096;
        for (int f = t; f < 4096; f += 256) {
            float a = wgo[f], c = wzo[f];
            int i = f >> 6, j = f & 63;
            #pragma unroll
            for (int b = 0; b < 4; b++) {
                float h = a * zql[b][j] + c * vgl[b][j];
                acc[b] += zql[b][i] * h;
            }
        }
        float wxv = Wx[o * 256 + t], wvv = Wv[o * 256 + t];
        #pragma unroll
        for (int b = 0; b < 4; b++)
            acc[b] += xq[b * 256 + t] * wxv + vq[b * 256 + t] * wvv;
        if (t < 64) {
            float wzz = Wz[o * 64 + t];
            #pragma unroll
            for (int b = 0; b < 4; b++) acc[b] += zql[b][t] * wzz;
        }
        #pragma unroll
        for (int b = 0; b < 4; b++) red[b][t] = acc[b];
        __syncthreads();
        for (int s = 128; s > 0; s >>= 1) {
            if (t < s) {
                #pragma unroll
                for (int b = 0; b < 4; b++) red[b][t] += red[b][t + s];
            }
            __syncthreads();
        }
        if (t < 4) ws[OFF_Q + t * 256 + o] = red[t][0] + bx[o] + bz[o] + bv[o];
        return;
    }

    // ---------------- k/v GEMM path ----------------
    int idx = blockIdx.x - 256;          // 0..127
    int which = idx >> 6;                // 0: k, 1: v
    int rem = idx & 63;
    int rt = rem & 15, jt = rem >> 4;
    const float *A, *Wm, *bias;
    float* C;
    if (which == 0) { A = xk; Wm = Wk;  bias = bk;  C = ws + OFF_K; }
    else            { A = xv; Wm = Wvl; bias = bvl; C = ws + OFF_V; }
    int r0 = rt * 64, j0 = jt * 64;
    int lr = t >> 2, lk = (t & 3) * 8;
    int tr = t >> 4, tc = t & 15;
    float acc[4][4];
    #pragma unroll
    for (int p = 0; p < 4; p++)
        #pragma unroll
        for (int q = 0; q < 4; q++) acc[p][q] = 0.f;
    for (int kc = 0; kc < 256; kc += 32) {
        f4 a0 = *(const f4*)(A  + (r0 + lr) * 256 + kc + lk);
        f4 a1 = *(const f4*)(A  + (r0 + lr) * 256 + kc + lk + 4);
        f4 b0 = *(const f4*)(Wm + (j0 + lr) * 256 + kc + lk);
        f4 b1 = *(const f4*)(Wm + (j0 + lr) * 256 + kc + lk + 4);
        __syncthreads();
        At[lk + 0][lr] = a0.x; At[lk + 1][lr] = a0.y; At[lk + 2][lr] = a0.z; At[lk + 3][lr] = a0.w;
        At[lk + 4][lr] = a1.x; At[lk + 5][lr] = a1.y; At[lk + 6][lr] = a1.z; At[lk + 7][lr] = a1.w;
        Bt[lk + 0][lr] = b0.x; Bt[lk + 1][lr] = b0.y; Bt[lk + 2][lr] = b0.z; Bt[lk + 3][lr] = b0.w;
        Bt[lk + 4][lr] = b1.x; Bt[lk + 5][lr] = b1.y; Bt[lk + 6][lr] = b1.z; Bt[lk + 7][lr] = b1.w;
        __syncthreads();
        #pragma unroll 8
        for (int kk = 0; kk < 32; kk++) {
            f4 av = *(const f4*)&At[kk][tr * 4];
            f4 bv4 = *(const f4*)&Bt[kk][tc * 4];
            float aa[4] = {av.x, av.y, av.z, av.w};
            float bb[4] = {bv4.x, bv4.y, bv4.z, bv4.w};
            #pragma unroll
            for (int p = 0; p < 4; p++)
                #pragma unroll
                for (int q = 0; q < 4; q++) acc[p][q] += aa[p] * bb[q];
        }
    }
    f4 b4 = *(const f4*)(bias + j0 + tc * 4);
    #pragma unroll
    for (int p = 0; p < 4; p++) {
        f4 o;
        o.x = acc[p][0] + b4.x; o.y = acc[p][1] + b4.y;
        o.z = acc[p][2] + b4.z; o.w = acc[p][3] + b4.w;
        *(f4*)(C + (r0 + tr * 4 + p) * 256 + j0 + tc * 4) = o;
    }
}

// =====================================================================
// K2: single-pass theta combine + T2.
// grid 256: block p owns jd slice [p*64, p*64+64), all 256 i, in-block
// i-reduction via LDS.  Also writes combined theta to OFF_TH.
// =====================================================================
__global__ __launch_bounds__(256) void ktheta2_kernel(
    const float* __restrict__ tb, const float* __restrict__ te,
    const float* __restrict__ to, float* __restrict__ ws)
{
    __shared__ float qls[1024];
    __shared__ float redls[16][16][16];   // [ichunk][col][b*4+comp]
    int t = threadIdx.x;
    int p = blockIdx.x;
    int col = t & 15, ic = t >> 4;
    #pragma unroll
    for (int f = 0; f < 4; f++) qls[f * 256 + t] = ws[OFF_Q + f * 256 + t];
    __syncthreads();
    int jdbase = p * 64 + col * 4;
    f4 acc[4];
    #pragma unroll
    for (int b = 0; b < 4; b++) { acc[b].x = 0.f; acc[b].y = 0.f; acc[b].z = 0.f; acc[b].w = 0.f; }
    #pragma unroll 4
    for (int ii = 0; ii < 16; ii++) {
        int i = ic * 16 + ii;
        int off = i * 16384 + jdbase;
        f4 a = *(const f4*)(tb + off);
        f4 e = *(const f4*)(te + off);
        f4 o = *(const f4*)(to + off);
        f4 th;
        th.x = a.x + 0.5f * e.x + 0.3f * o.x;
        th.y = a.y + 0.5f * e.y + 0.3f * o.y;
        th.z = a.z + 0.5f * e.z + 0.3f * o.z;
        th.w = a.w + 0.5f * e.w + 0.3f * o.w;
        *(f4*)(ws + OFF_TH + off) = th;
        #pragma unroll
        for (int b = 0; b < 4; b++) {
            float qv = qls[b * 256 + i];
            acc[b].x += qv * th.x; acc[b].y += qv * th.y;
            acc[b].z += qv * th.z; acc[b].w += qv * th.w;
        }
    }
    #pragma unroll
    for (int b = 0; b < 4; b++) {
        redls[ic][col][b * 4 + 0] = acc[b].x;
        redls[ic][col][b * 4 + 1] = acc[b].y;
        redls[ic][col][b * 4 + 2] = acc[b].z;
        redls[ic][col][b * 4 + 3] = acc[b].w;
    }
    __syncthreads();
    {
        int colx = t >> 4, e = t & 15;
        float s = 0.f;
        #pragma unroll
        for (int c = 0; c < 16; c++) s += redls[c][colx][e];
        int bb = e >> 2, comp = e & 3;
        ws[OFF_T2 + bb * 16384 + p * 64 + colx * 4 + comp] = s;
    }
}

// =====================================================================
// K3: GEMM-shaped scores.  M[n,d] = sum_j k[b,n,j]*T2[b,j,d]; fold qk.
// grid (16 = 4b x 4ntile, 4 dtile).  Writes SNUMP/SD2P partials.
// =====================================================================
__global__ __launch_bounds__(256) void kscore2_kernel(
    const float* __restrict__ zq, const float* __restrict__ zk,
    float* __restrict__ ws)
{
    __shared__ float kls[64][33];
    __shared__ float t2ls[32][16];
    __shared__ float qls[32];
    int t = threadIdx.x;
    int bx = blockIdx.x;
    int b = bx >> 2, nt = bx & 3;
    int dt = blockIdx.y;
    int nl = t >> 2, dq = t & 3;
    int n = nt * 64 + nl;
    const float* kb = ws + OFF_K + (b * 256 + nt * 64) * 256;
    const float* T2b = ws + OFF_T2 + b * 16384;
    const float* qb = ws + OFF_Q + b * 256;
    float acc[4] = {0.f, 0.f, 0.f, 0.f};
    float qk = 0.f;
    for (int j0 = 0; j0 < 256; j0 += 32) {
        __syncthreads();
        {   // stage k tile [64n x 32j]
            int row = t >> 2, colk = (t & 3) * 8;
            f4 a0 = *(const f4*)(kb + row * 256 + j0 + colk);
            f4 a1 = *(const f4*)(kb + row * 256 + j0 + colk + 4);
            kls[row][colk + 0] = a0.x; kls[row][colk + 1] = a0.y;
            kls[row][colk + 2] = a0.z; kls[row][colk + 3] = a0.w;
            kls[row][colk + 4] = a1.x; kls[row][colk + 5] = a1.y;
            kls[row][colk + 6] = a1.z; kls[row][colk + 7] = a1.w;
        }
        {   // stage T2 tile [32j x 16d]
            int e = t * 2; int jj = e >> 4; int dd = e & 15;
            const float* pp = T2b + (j0 + jj) * 64 + dt * 16 + dd;
            t2ls[jj][dd] = pp[0];
            t2ls[jj][dd + 1] = pp[1];
        }
        if (t < 32) qls[t] = qb[j0 + t];
        __syncthreads();
        #pragma unroll
        for (int jj = 0; jj < 32; jj++) {
            float kv = kls[nl][jj];
            f4 t4 = *(const f4*)&t2ls[jj][dq * 4];
            acc[0] += kv * t4.x; acc[1] += kv * t4.y;
            acc[2] += kv * t4.z; acc[3] += kv * t4.w;
            qk += kv * qls[jj];
        }
    }
    int d0 = dt * 16 + dq * 4;
    f4 zq4 = *(const f4*)(zq + b * 64 + d0);
    f4 zk4 = *(const f4*)(zk + (b * 256 + n) * 64 + d0);
    float dx = zq4.x - zk4.x, dy = zq4.y - zk4.y;
    float dz = zq4.z - zk4.z, dw = zq4.w - zk4.w;
    float s1 = acc[0] * dx + acc[1] * dy + acc[2] * dz + acc[3] * dw;
    float s2 = dx * dx + dy * dy + dz * dz + dw * dw;
    s1 += __shfl_xor(s1, 1, 64); s1 += __shfl_xor(s1, 2, 64);
    s2 += __shfl_xor(s2, 1, 64); s2 += __shfl_xor(s2, 2, 64);
    if (dq == 0) {
        ws[OFF_SNUMP + (dt * 4 + b) * 256 + n] = (dt == 0 ? qk : 0.f) - s1;
        ws[OFF_SD2P  + (dt * 4 + b) * 256 + n] = s2;
    }
}

// =====================================================================
// K4: fused softmax + screening + renorm + S + base.
// grid 64 = 4b x 16 jtile(16j).  Each block recomputes softmax for its b
// (cheap: 4KB partial reduce), jt==0 blocks write attention output.
// =====================================================================
__global__ __launch_bounds__(256) void ks2f_kernel(
    const float* __restrict__ zq, const float* __restrict__ zk,
    const int* __restrict__ level,
    float* __restrict__ ws, float* __restrict__ dout)
{
    __shared__ float vls[32][17];
    __shared__ float dls[32][64];
    __shared__ float zqs[64];
    __shared__ float attn[256];
    __shared__ float sh[4];
    int t = threadIdx.x;
    int b = blockIdx.x >> 4, jt = blockIdx.x & 15;
    if (t < 64) zqs[t] = zq[b * 64 + t];
    __syncthreads();
    // ---- lambda ----
    if (t < 64) {
        float zv = zqs[t];
        float v = zv * zv;
        #pragma unroll
        for (int off = 32; off; off >>= 1) v += __shfl_xor(v, off, 64);
        if (t == 0) sh[0] = 2.f / (1.f - v + 1e-6f);
    }
    __syncthreads();
    float lam = sh[0];
    __syncthreads();
    float tau = 16.f / lam;
    float sigma = expf(-(float)level[0]);
    float snum = 0.f, sd2 = 0.f;
    #pragma unroll
    for (int dt = 0; dt < 4; dt++) {
        snum += ws[OFF_SNUMP + (dt * 4 + b) * 256 + t];
        sd2  += ws[OFF_SD2P  + (dt * 4 + b) * 256 + t];
    }
    float sc = snum / (tau + 1e-6f);
    int wid = t >> 6;
    float m = sc;
    #pragma unroll
    for (int off = 32; off; off >>= 1) m = fmaxf(m, __shfl_xor(m, off, 64));
    if ((t & 63) == 0) sh[wid] = m;
    __syncthreads();
    m = fmaxf(fmaxf(sh[0], sh[1]), fmaxf(sh[2], sh[3]));
    __syncthreads();
    float e = expf(sc - m);
    float s = e;
    #pragma unroll
    for (int off = 32; off; off >>= 1) s += __shfl_xor(s, off, 64);
    if ((t & 63) == 0) sh[wid] = s;
    __syncthreads();
    float Z = sh[0] + sh[1] + sh[2] + sh[3];
    __syncthreads();
    float a = (e / Z) * expf(-sigma * 0.5f * lam * lam * sd2);
    s = a;
    #pragma unroll
    for (int off = 32; off; off >>= 1) s += __shfl_xor(s, off, 64);
    if ((t & 63) == 0) sh[wid] = s;
    __syncthreads();
    float Z2 = sh[0] + sh[1] + sh[2] + sh[3];
    float af = a / (Z2 + 1e-6f);
    attn[t] = af;
    if (jt == 0) dout[1024 + b * 256 + t] = af;
    // ---- S phase ----
    int jl = t >> 4, dq = t & 15, d0 = dq * 4;
    const float* vb = ws + OFF_V + b * 65536;
    const float* zkb = zk + b * 16384;
    float acc[4] = {0.f, 0.f, 0.f, 0.f};
    float bacc = 0.f;
    for (int n0 = 0; n0 < 256; n0 += 32) {
        __syncthreads();
        {   // stage v [32n x 16j]
            int e2 = t * 2; int nn = e2 >> 4; int jj = e2 & 15;
            const float* pp = vb + (n0 + nn) * 256 + jt * 16 + jj;
            vls[nn][jj] = pp[0];
            vls[nn][jj + 1] = pp[1];
        }
        {   // stage delta [32n x 64d]
            int e2 = t * 8; int nn = e2 >> 6; int dd = e2 & 63;
            f4 a4 = *(const f4*)(zkb + (n0 + nn) * 64 + dd);
            f4 b4 = *(const f4*)(zkb + (n0 + nn) * 64 + dd + 4);
            dls[nn][dd + 0] = zqs[dd + 0] - a4.x;
            dls[nn][dd + 1] = zqs[dd + 1] - a4.y;
            dls[nn][dd + 2] = zqs[dd + 2] - a4.z;
            dls[nn][dd + 3] = zqs[dd + 3] - a4.w;
            dls[nn][dd + 4] = zqs[dd + 4] - b4.x;
            dls[nn][dd + 5] = zqs[dd + 5] - b4.y;
            dls[nn][dd + 6] = zqs[dd + 6] - b4.z;
            dls[nn][dd + 7] = zqs[dd + 7] - b4.w;
        }
        __syncthreads();
        #pragma unroll
        for (int nn = 0; nn < 32; nn++) {
            float avv = attn[n0 + nn] * vls[nn][jl];
            f4 d4 = *(const f4*)&dls[nn][d0];
            acc[0] += avv * d4.x; acc[1] += avv * d4.y;
            acc[2] += avv * d4.z; acc[3] += avv * d4.w;
            bacc += avv;
        }
    }
    float* Sb = ws + OFF_S + b * 16384;
    f4 o; o.x = acc[0]; o.y = acc[1]; o.z = acc[2]; o.w = acc[3];
    *(f4*)(Sb + (jt * 16 + jl) * 64 + d0) = o;
    if (dq == 0) ws[OFF_BASE + b * 256 + jt * 16 + jl] = bacc;
}

// =====================================================================
// K5: out[b,i] = base[b,i] - sum_jd thcomb[i,jd]*S[b,jd]
// =====================================================================
__global__ __launch_bounds__(256) void koutc_kernel(
    float* __restrict__ ws, float* __restrict__ dout)
{
    __shared__ float red[4][256];
    int t = threadIdx.x, i = blockIdx.x;
    const float* S = ws + OFF_S;
    const float* TH = ws + OFF_TH;
    float acc[4] = {0.f, 0.f, 0.f, 0.f};
    #pragma unroll 4
    for (int f = 0; f < 16; f++) {
        int jd = f * 1024 + t * 4;
        f4 th = *(const f4*)(TH + i * 16384 + jd);
        #pragma unroll
        for (int b = 0; b < 4; b++) {
            f4 s4 = *(const f4*)(S + b * 16384 + jd);
            acc[b] += th.x * s4.x + th.y * s4.y + th.z * s4.z + th.w * s4.w;
        }
    }
    #pragma unroll
    for (int b = 0; b < 4; b++) red[b][t] = acc[b];
    __syncthreads();
    for (int s = 128; s > 0; s >>= 1) {
        if (t < s) {
            #pragma unroll
            for (int b = 0; b < 4; b++) red[b][t] += red[b][t + s];
        }
        __syncthreads();
    }
    if (t < 4) {
        float bs = ws[OFF_BASE + t * 256 + i];
        dout[t * 256 + i] = bs - red[t][0];
    }
}

extern "C" void kernel_launch(void* const* d_in, const int* in_sizes, int n_in,
                              void* d_out, int out_size, void* d_ws, size_t ws_size,
                              hipStream_t stream)
{
    (void)in_sizes; (void)n_in; (void)out_size; (void)ws_size;
    const float* zq  = (const float*)d_in[0];
    const float* zk  = (const float*)d_in[1];
    const float* xq  = (const float*)d_in[2];
    const float* xk  = (const float*)d_in[3];
    const float* xv  = (const float*)d_in[4];
    const float* vq  = (const float*)d_in[5];
    const float* vg  = (const float*)d_in[6];
    const float* Wx  = (const float*)d_in[7];
    const float* bx  = (const float*)d_in[8];
    const float* Wz  = (const float*)d_in[9];
    const float* bz  = (const float*)d_in[10];
    const float* Wv  = (const float*)d_in[11];
    const float* bv  = (const float*)d_in[12];
    const float* wg  = (const float*)d_in[13];
    const float* wzv = (const float*)d_in[14];
    const float* Wk  = (const float*)d_in[15];
    const float* bk  = (const float*)d_in[16];
    const float* Wvl = (const float*)d_in[17];
    const float* bvl = (const float*)d_in[18];
    const float* tb  = (const float*)d_in[19];
    const float* te  = (const float*)d_in[20];
    const float* to  = (const float*)d_in[21];
    const int* level = (const int*)d_in[22];
    float* ws = (float*)d_ws;
    float* dout = (float*)d_out;

    kprep_kernel<<<dim3(384), dim3(256), 0, stream>>>(
        zq, xq, vq, vg, Wx, bx, Wz, bz, Wv, bv, wg, wzv,
        xk, xv, Wk, bk, Wvl, bvl, ws);
    ktheta2_kernel<<<dim3(256), dim3(256), 0, stream>>>(tb, te, to, ws);
    kscore2_kernel<<<dim3(16, 4), dim3(256), 0, stream>>>(zq, zk, ws);
    ks2f_kernel<<<dim3(64), dim3(256), 0, stream>>>(zq, zk, level, ws, dout);
    koutc_kernel<<<dim3(256), dim3(256), 0, stream>>>(ws, dout);
}

// Round 4
// 188.670 us; speedup vs baseline: 1.1455x; 1.0080x over previous
//
#include <hip/hip_runtime.h>
#include <hip/hip_bf16.h>

// B=4, N=256, D=256, DL=64
typedef float4 f4;

// ---- workspace layout (float offsets) ----
#define OFF_K     0          // k = x_key@Wk.T + bk       [4*256, 256]
#define OFF_V     262144     // v = x_value@Wvl.T + bvl   [4*256, 256]
#define OFF_Q     524288     // q                          [4, 256]
#define OFF_T2    525312     // T2[b][j][d]                [4, 16384]
#define OFF_SNUMP 590848     // score-num partials [4dt][4b][256]
#define OFF_SD2P  594944     // sum(delta^2) partials [4dt][4b][256]
#define OFF_BASE  599040     // base[b][i]                 [4, 256]
#define OFF_S     600064     // S[b][jd]                   [4, 16384]
#define OFF_TH    665600     // combined theta, BF16 packed [256][16384] (8.4 MB)

// round-to-nearest-even f32 -> bf16 bits
__device__ __forceinline__ unsigned short f2bf(float v) {
    unsigned int u = __float_as_uint(v);
    unsigned int r = (u + 0x7FFFu + ((u >> 16) & 1u)) >> 16;
    return (unsigned short)r;
}

// =====================================================================
// K1: fused q-projection (blocks 0..255) + k/v GEMM (blocks 256..383)
// =====================================================================
__global__ __launch_bounds__(256) void kprep_kernel(
    const float* __restrict__ zq, const float* __restrict__ xq,
    const float* __restrict__ vq, const float* __restrict__ vg,
    const float* __restrict__ Wx, const float* __restrict__ bx,
    const float* __restrict__ Wz, const float* __restrict__ bz,
    const float* __restrict__ Wv, const float* __restrict__ bv,
    const float* __restrict__ wg, const float* __restrict__ wzv,
    const float* __restrict__ xk, const float* __restrict__ xv,
    const float* __restrict__ Wk, const float* __restrict__ bk,
    const float* __restrict__ Wvl, const float* __restrict__ bvl,
    float* __restrict__ ws)
{
    __shared__ float zql[4][64], vgl[4][64];
    __shared__ float red[4][256];
    __shared__ float At[32][68];
    __shared__ float Bt[32][68];
    int t = threadIdx.x;

    if (blockIdx.x < 256) {
        // ---------------- q path ----------------
        int o = blockIdx.x;
        zql[t >> 6][t & 63] = zq[t];
        vgl[t >> 6][t & 63] = vg[t];
        __syncthreads();
        float acc[4] = {0.f, 0.f, 0.f, 0.f};
        const float* wgo = wg + o * 4096;
        const float* wzo = wzv + o * 4096;
        for (int f = t; f < 4096; f += 256) {
            float a = wgo[f], c = wzo[f];
            int i = f >> 6, j = f & 63;
            #pragma unroll
            for (int b = 0; b < 4; b++) {
                float h = a * zql[b][j] + c * vgl[b][j];
                acc[b] += zql[b][i] * h;
            }
        }
        float wxv = Wx[o * 256 + t], wvv = Wv[o * 256 + t];
        #pragma unroll
        for (int b = 0; b < 4; b++)
            acc[b] += xq[b * 256 + t] * wxv + vq[b * 256 + t] * wvv;
        if (t < 64) {
            float wzz = Wz[o * 64 + t];
            #pragma unroll
            for (int b = 0; b < 4; b++) acc[b] += zql[b][t] * wzz;
        }
        #pragma unroll
        for (int b = 0; b < 4; b++) red[b][t] = acc[b];
        __syncthreads();
        for (int s = 128; s > 0; s >>= 1) {
            if (t < s) {
                #pragma unroll
                for (int b = 0; b < 4; b++) red[b][t] += red[b][t + s];
            }
            __syncthreads();
        }
        if (t < 4) ws[OFF_Q + t * 256 + o] = red[t][0] + bx[o] + bz[o] + bv[o];
        return;
    }

    // ---------------- k/v GEMM path ----------------
    int idx = blockIdx.x - 256;          // 0..127
    int which = idx >> 6;                // 0: k, 1: v
    int rem = idx & 63;
    int rt = rem & 15, jt = rem >> 4;
    const float *A, *Wm, *bias;
    float* C;
    if (which == 0) { A = xk; Wm = Wk;  bias = bk;  C = ws + OFF_K; }
    else            { A = xv; Wm = Wvl; bias = bvl; C = ws + OFF_V; }
    int r0 = rt * 64, j0 = jt * 64;
    int lr = t >> 2, lk = (t & 3) * 8;
    int tr = t >> 4, tc = t & 15;
    float acc[4][4];
    #pragma unroll
    for (int p = 0; p < 4; p++)
        #pragma unroll
        for (int q = 0; q < 4; q++) acc[p][q] = 0.f;
    for (int kc = 0; kc < 256; kc += 32) {
        f4 a0 = *(const f4*)(A  + (r0 + lr) * 256 + kc + lk);
        f4 a1 = *(const f4*)(A  + (r0 + lr) * 256 + kc + lk + 4);
        f4 b0 = *(const f4*)(Wm + (j0 + lr) * 256 + kc + lk);
        f4 b1 = *(const f4*)(Wm + (j0 + lr) * 256 + kc + lk + 4);
        __syncthreads();
        At[lk + 0][lr] = a0.x; At[lk + 1][lr] = a0.y; At[lk + 2][lr] = a0.z; At[lk + 3][lr] = a0.w;
        At[lk + 4][lr] = a1.x; At[lk + 5][lr] = a1.y; At[lk + 6][lr] = a1.z; At[lk + 7][lr] = a1.w;
        Bt[lk + 0][lr] = b0.x; Bt[lk + 1][lr] = b0.y; Bt[lk + 2][lr] = b0.z; Bt[lk + 3][lr] = b0.w;
        Bt[lk + 4][lr] = b1.x; Bt[lk + 5][lr] = b1.y; Bt[lk + 6][lr] = b1.z; Bt[lk + 7][lr] = b1.w;
        __syncthreads();
        #pragma unroll 8
        for (int kk = 0; kk < 32; kk++) {
            f4 av = *(const f4*)&At[kk][tr * 4];
            f4 bv4 = *(const f4*)&Bt[kk][tc * 4];
            float aa[4] = {av.x, av.y, av.z, av.w};
            float bb[4] = {bv4.x, bv4.y, bv4.z, bv4.w};
            #pragma unroll
            for (int p = 0; p < 4; p++)
                #pragma unroll
                for (int q = 0; q < 4; q++) acc[p][q] += aa[p] * bb[q];
        }
    }
    f4 b4 = *(const f4*)(bias + j0 + tc * 4);
    #pragma unroll
    for (int p = 0; p < 4; p++) {
        f4 o;
        o.x = acc[p][0] + b4.x; o.y = acc[p][1] + b4.y;
        o.z = acc[p][2] + b4.z; o.w = acc[p][3] + b4.w;
        *(f4*)(C + (r0 + tr * 4 + p) * 256 + j0 + tc * 4) = o;
    }
}

// =====================================================================
// K2: single-pass theta combine + T2.  Combined theta stored as BF16.
// grid 256: block p owns jd slice [p*64, p*64+64), all 256 i, in-block
// i-reduction via LDS.
// =====================================================================
__global__ __launch_bounds__(256) void ktheta2_kernel(
    const float* __restrict__ tb, const float* __restrict__ te,
    const float* __restrict__ to, float* __restrict__ ws)
{
    __shared__ float qls[1024];
    __shared__ float redls[16][16][16];   // [ichunk][col][b*4+comp]
    int t = threadIdx.x;
    int p = blockIdx.x;
    int col = t & 15, ic = t >> 4;
    uint2* THb = (uint2*)(ws + OFF_TH);
    #pragma unroll
    for (int f = 0; f < 4; f++) qls[f * 256 + t] = ws[OFF_Q + f * 256 + t];
    __syncthreads();
    int jdbase = p * 64 + col * 4;
    f4 acc[4];
    #pragma unroll
    for (int b = 0; b < 4; b++) { acc[b].x = 0.f; acc[b].y = 0.f; acc[b].z = 0.f; acc[b].w = 0.f; }
    #pragma unroll 4
    for (int ii = 0; ii < 16; ii++) {
        int i = ic * 16 + ii;
        int off = i * 16384 + jdbase;
        f4 a = *(const f4*)(tb + off);
        f4 e = *(const f4*)(te + off);
        f4 o = *(const f4*)(to + off);
        f4 th;
        th.x = a.x + 0.5f * e.x + 0.3f * o.x;
        th.y = a.y + 0.5f * e.y + 0.3f * o.y;
        th.z = a.z + 0.5f * e.z + 0.3f * o.z;
        th.w = a.w + 0.5f * e.w + 0.3f * o.w;
        uint2 pk;
        pk.x = (unsigned)f2bf(th.x) | ((unsigned)f2bf(th.y) << 16);
        pk.y = (unsigned)f2bf(th.z) | ((unsigned)f2bf(th.w) << 16);
        THb[off >> 2] = pk;
        #pragma unroll
        for (int b = 0; b < 4; b++) {
            float qv = qls[b * 256 + i];
            acc[b].x += qv * th.x; acc[b].y += qv * th.y;
            acc[b].z += qv * th.z; acc[b].w += qv * th.w;
        }
    }
    #pragma unroll
    for (int b = 0; b < 4; b++) {
        redls[ic][col][b * 4 + 0] = acc[b].x;
        redls[ic][col][b * 4 + 1] = acc[b].y;
        redls[ic][col][b * 4 + 2] = acc[b].z;
        redls[ic][col][b * 4 + 3] = acc[b].w;
    }
    __syncthreads();
    {
        int colx = t >> 4, e = t & 15;
        float s = 0.f;
        #pragma unroll
        for (int c = 0; c < 16; c++) s += redls[c][colx][e];
        int bb = e >> 2, comp = e & 3;
        ws[OFF_T2 + bb * 16384 + p * 64 + colx * 4 + comp] = s;
    }
}

// =====================================================================
// K3: GEMM-shaped scores.  M[n,d] = sum_j k[b,n,j]*T2[b,j,d]; fold qk.
// grid (16 = 4b x 4ntile, 4 dtile).  Writes SNUMP/SD2P partials.
// =====================================================================
__global__ __launch_bounds__(256) void kscore2_kernel(
    const float* __restrict__ zq, const float* __restrict__ zk,
    float* __restrict__ ws)
{
    __shared__ float kls[64][33];
    __shared__ float t2ls[32][16];
    __shared__ float qls[32];
    int t = threadIdx.x;
    int bx = blockIdx.x;
    int b = bx >> 2, nt = bx & 3;
    int dt = blockIdx.y;
    int nl = t >> 2, dq = t & 3;
    int n = nt * 64 + nl;
    const float* kb = ws + OFF_K + (b * 256 + nt * 64) * 256;
    const float* T2b = ws + OFF_T2 + b * 16384;
    const float* qb = ws + OFF_Q + b * 256;
    float acc[4] = {0.f, 0.f, 0.f, 0.f};
    float qk = 0.f;
    for (int j0 = 0; j0 < 256; j0 += 32) {
        __syncthreads();
        {   // stage k tile [64n x 32j]
            int row = t >> 2, colk = (t & 3) * 8;
            f4 a0 = *(const f4*)(kb + row * 256 + j0 + colk);
            f4 a1 = *(const f4*)(kb + row * 256 + j0 + colk + 4);
            kls[row][colk + 0] = a0.x; kls[row][colk + 1] = a0.y;
            kls[row][colk + 2] = a0.z; kls[row][colk + 3] = a0.w;
            kls[row][colk + 4] = a1.x; kls[row][colk + 5] = a1.y;
            kls[row][colk + 6] = a1.z; kls[row][colk + 7] = a1.w;
        }
        {   // stage T2 tile [32j x 16d]
            int e = t * 2; int jj = e >> 4; int dd = e & 15;
            const float* pp = T2b + (j0 + jj) * 64 + dt * 16 + dd;
            t2ls[jj][dd] = pp[0];
            t2ls[jj][dd + 1] = pp[1];
        }
        if (t < 32) qls[t] = qb[j0 + t];
        __syncthreads();
        #pragma unroll
        for (int jj = 0; jj < 32; jj++) {
            float kv = kls[nl][jj];
            f4 t4 = *(const f4*)&t2ls[jj][dq * 4];
            acc[0] += kv * t4.x; acc[1] += kv * t4.y;
            acc[2] += kv * t4.z; acc[3] += kv * t4.w;
            qk += kv * qls[jj];
        }
    }
    int d0 = dt * 16 + dq * 4;
    f4 zq4 = *(const f4*)(zq + b * 64 + d0);
    f4 zk4 = *(const f4*)(zk + (b * 256 + n) * 64 + d0);
    float dx = zq4.x - zk4.x, dy = zq4.y - zk4.y;
    float dz = zq4.z - zk4.z, dw = zq4.w - zk4.w;
    float s1 = acc[0] * dx + acc[1] * dy + acc[2] * dz + acc[3] * dw;
    float s2 = dx * dx + dy * dy + dz * dz + dw * dw;
    s1 += __shfl_xor(s1, 1, 64); s1 += __shfl_xor(s1, 2, 64);
    s2 += __shfl_xor(s2, 1, 64); s2 += __shfl_xor(s2, 2, 64);
    if (dq == 0) {
        ws[OFF_SNUMP + (dt * 4 + b) * 256 + n] = (dt == 0 ? qk : 0.f) - s1;
        ws[OFF_SD2P  + (dt * 4 + b) * 256 + n] = s2;
    }
}

// =====================================================================
// K4: fused softmax + screening + renorm + S + base.
// grid 64 = 4b x 16 jtile(16j).
// =====================================================================
__global__ __launch_bounds__(256) void ks2f_kernel(
    const float* __restrict__ zq, const float* __restrict__ zk,
    const int* __restrict__ level,
    float* __restrict__ ws, float* __restrict__ dout)
{
    __shared__ float vls[32][17];
    __shared__ float dls[32][64];
    __shared__ float zqs[64];
    __shared__ float attn[256];
    __shared__ float sh[4];
    int t = threadIdx.x;
    int b = blockIdx.x >> 4, jt = blockIdx.x & 15;
    if (t < 64) zqs[t] = zq[b * 64 + t];
    __syncthreads();
    // ---- lambda ----
    if (t < 64) {
        float zv = zqs[t];
        float v = zv * zv;
        #pragma unroll
        for (int off = 32; off; off >>= 1) v += __shfl_xor(v, off, 64);
        if (t == 0) sh[0] = 2.f / (1.f - v + 1e-6f);
    }
    __syncthreads();
    float lam = sh[0];
    __syncthreads();
    float tau = 16.f / lam;
    float sigma = expf(-(float)level[0]);
    float snum = 0.f, sd2 = 0.f;
    #pragma unroll
    for (int dt = 0; dt < 4; dt++) {
        snum += ws[OFF_SNUMP + (dt * 4 + b) * 256 + t];
        sd2  += ws[OFF_SD2P  + (dt * 4 + b) * 256 + t];
    }
    float sc = snum / (tau + 1e-6f);
    int wid = t >> 6;
    float m = sc;
    #pragma unroll
    for (int off = 32; off; off >>= 1) m = fmaxf(m, __shfl_xor(m, off, 64));
    if ((t & 63) == 0) sh[wid] = m;
    __syncthreads();
    m = fmaxf(fmaxf(sh[0], sh[1]), fmaxf(sh[2], sh[3]));
    __syncthreads();
    float e = expf(sc - m);
    float s = e;
    #pragma unroll
    for (int off = 32; off; off >>= 1) s += __shfl_xor(s, off, 64);
    if ((t & 63) == 0) sh[wid] = s;
    __syncthreads();
    float Z = sh[0] + sh[1] + sh[2] + sh[3];
    __syncthreads();
    float a = (e / Z) * expf(-sigma * 0.5f * lam * lam * sd2);
    s = a;
    #pragma unroll
    for (int off = 32; off; off >>= 1) s += __shfl_xor(s, off, 64);
    if ((t & 63) == 0) sh[wid] = s;
    __syncthreads();
    float Z2 = sh[0] + sh[1] + sh[2] + sh[3];
    float af = a / (Z2 + 1e-6f);
    attn[t] = af;
    if (jt == 0) dout[1024 + b * 256 + t] = af;
    // ---- S phase ----
    int jl = t >> 4, dq = t & 15, d0 = dq * 4;
    const float* vb = ws + OFF_V + b * 65536;
    const float* zkb = zk + b * 16384;
    float acc[4] = {0.f, 0.f, 0.f, 0.f};
    float bacc = 0.f;
    for (int n0 = 0; n0 < 256; n0 += 32) {
        __syncthreads();
        {   // stage v [32n x 16j]
            int e2 = t * 2; int nn = e2 >> 4; int jj = e2 & 15;
            const float* pp = vb + (n0 + nn) * 256 + jt * 16 + jj;
            vls[nn][jj] = pp[0];
            vls[nn][jj + 1] = pp[1];
        }
        {   // stage delta [32n x 64d]
            int e2 = t * 8; int nn = e2 >> 6; int dd = e2 & 63;
            f4 a4 = *(const f4*)(zkb + (n0 + nn) * 64 + dd);
            f4 b4 = *(const f4*)(zkb + (n0 + nn) * 64 + dd + 4);
            dls[nn][dd + 0] = zqs[dd + 0] - a4.x;
            dls[nn][dd + 1] = zqs[dd + 1] - a4.y;
            dls[nn][dd + 2] = zqs[dd + 2] - a4.z;
            dls[nn][dd + 3] = zqs[dd + 3] - a4.w;
            dls[nn][dd + 4] = zqs[dd + 4] - b4.x;
            dls[nn][dd + 5] = zqs[dd + 5] - b4.y;
            dls[nn][dd + 6] = zqs[dd + 6] - b4.z;
            dls[nn][dd + 7] = zqs[dd + 7] - b4.w;
        }
        __syncthreads();
        #pragma unroll
        for (int nn = 0; nn < 32; nn++) {
            float avv = attn[n0 + nn] * vls[nn][jl];
            f4 d4 = *(const f4*)&dls[nn][d0];
            acc[0] += avv * d4.x; acc[1] += avv * d4.y;
            acc[2] += avv * d4.z; acc[3] += avv * d4.w;
            bacc += avv;
        }
    }
    float* Sb = ws + OFF_S + b * 16384;
    f4 o; o.x = acc[0]; o.y = acc[1]; o.z = acc[2]; o.w = acc[3];
    *(f4*)(Sb + (jt * 16 + jl) * 64 + d0) = o;
    if (dq == 0) ws[OFF_BASE + b * 256 + jt * 16 + jl] = bacc;
}

// =====================================================================
// K5: out[b,i] = base[b,i] - sum_jd thcomb_bf16[i,jd]*S[b,jd]
// =====================================================================
__global__ __launch_bounds__(256) void koutc_kernel(
    float* __restrict__ ws, float* __restrict__ dout)
{
    __shared__ float red[4][256];
    int t = threadIdx.x, i = blockIdx.x;
    const float* S = ws + OFF_S;
    const uint4* THb = (const uint4*)(ws + OFF_TH);
    float acc[4] = {0.f, 0.f, 0.f, 0.f};
    #pragma unroll 4
    for (int f = 0; f < 8; f++) {
        int jd = f * 2048 + t * 8;
        uint4 u = THb[(i * 16384 + jd) >> 3];
        float t0 = __uint_as_float(u.x << 16);
        float t1 = __uint_as_float(u.x & 0xFFFF0000u);
        float t2 = __uint_as_float(u.y << 16);
        float t3 = __uint_as_float(u.y & 0xFFFF0000u);
        float t4 = __uint_as_float(u.z << 16);
        float t5 = __uint_as_float(u.z & 0xFFFF0000u);
        float t6 = __uint_as_float(u.w << 16);
        float t7 = __uint_as_float(u.w & 0xFFFF0000u);
        #pragma unroll
        for (int b = 0; b < 4; b++) {
            f4 s0 = *(const f4*)(S + b * 16384 + jd);
            f4 s1 = *(const f4*)(S + b * 16384 + jd + 4);
            acc[b] += t0 * s0.x + t1 * s0.y + t2 * s0.z + t3 * s0.w
                    + t4 * s1.x + t5 * s1.y + t6 * s1.z + t7 * s1.w;
        }
    }
    #pragma unroll
    for (int b = 0; b < 4; b++) red[b][t] = acc[b];
    __syncthreads();
    for (int s = 128; s > 0; s >>= 1) {
        if (t < s) {
            #pragma unroll
            for (int b = 0; b < 4; b++) red[b][t] += red[b][t + s];
        }
        __syncthreads();
    }
    if (t < 4) {
        float bs = ws[OFF_BASE + t * 256 + i];
        dout[t * 256 + i] = bs - red[t][0];
    }
}

extern "C" void kernel_launch(void* const* d_in, const int* in_sizes, int n_in,
                              void* d_out, int out_size, void* d_ws, size_t ws_size,
                              hipStream_t stream)
{
    (void)in_sizes; (void)n_in; (void)out_size; (void)ws_size;
    const float* zq  = (const float*)d_in[0];
    const float* zk  = (const float*)d_in[1];
    const float* xq  = (const float*)d_in[2];
    const float* xk  = (const float*)d_in[3];
    const float* xv  = (const float*)d_in[4];
    const float* vq  = (const float*)d_in[5];
    const float* vg  = (const float*)d_in[6];
    const float* Wx  = (const float*)d_in[7];
    const float* bx  = (const float*)d_in[8];
    const float* Wz  = (const float*)d_in[9];
    const float* bz  = (const float*)d_in[10];
    const float* Wv  = (const float*)d_in[11];
    const float* bv  = (const float*)d_in[12];
    const float* wg  = (const float*)d_in[13];
    const float* wzv = (const float*)d_in[14];
    const float* Wk  = (const float*)d_in[15];
    const float* bk  = (const float*)d_in[16];
    const float* Wvl = (const float*)d_in[17];
    const float* bvl = (const float*)d_in[18];
    const float* tb  = (const float*)d_in[19];
    const float* te  = (const float*)d_in[20];
    const float* to  = (const float*)d_in[21];
    const int* level = (const int*)d_in[22];
    float* ws = (float*)d_ws;
    float* dout = (float*)d_out;

    kprep_kernel<<<dim3(384), dim3(256), 0, stream>>>(
        zq, xq, vq, vg, Wx, bx, Wz, bz, Wv, bv, wg, wzv,
        xk, xv, Wk, bk, Wvl, bvl, ws);
    ktheta2_kernel<<<dim3(256), dim3(256), 0, stream>>>(tb, te, to, ws);
    kscore2_kernel<<<dim3(16, 4), dim3(256), 0, stream>>>(zq, zk, ws);
    ks2f_kernel<<<dim3(64), dim3(256), 0, stream>>>(zq, zk, level, ws, dout);
    koutc_kernel<<<dim3(256), dim3(256), 0, stream>>>(ws, dout);
}